// Round 5
// baseline (692.799 us; speedup 1.0000x reference)
//
#include <hip/hip_runtime.h>
#include <stdint.h>

// Problem constants
#define B_   8
#define C_   256
#define N_   2304          // 48*48 spatial
#define HID  128
#define O3   384           // 3*HID
#define NH   4
#define SCALE 0.0625f      // 256^-0.5
#define QPRE 0.09016844f   // SCALE * log2(e): q pre-scale so p = exp2(q.k)

typedef unsigned short u16;
typedef short  bf8  __attribute__((ext_vector_type(8)));   // 8 bf16 (4 VGPRs) MFMA A/B frag
typedef float  f4   __attribute__((ext_vector_type(4)));   // MFMA C/D frag
typedef u16    u16x8 __attribute__((ext_vector_type(8)));

#define MFMA(a,b,c) __builtin_amdgcn_mfma_f32_16x16x32_bf16((a),(b),(c),0,0,0)

static __device__ __forceinline__ u16 f2bf(float f){
    union { float f; unsigned int i; } v; v.f = f;
    unsigned int r = v.i + 0x7FFFu + ((v.i >> 16) & 1u);   // round-to-nearest-even
    return (u16)(r >> 16);
}
static __device__ __forceinline__ float fexp2(float x){
#if __has_builtin(__builtin_amdgcn_exp2f)
    return __builtin_amdgcn_exp2f(x);
#else
    return __expf(x * 0.69314718f);
#endif
}
static __device__ __forceinline__ u16 hi16(float f){       // truncating f32->bf16
    union { float f; unsigned int i; } v; v.f = f;
    return (u16)(v.i >> 16);
}

// ---------------------------------------------------------------------------
// K0a: convert embed weights fp32 -> bf16.
__global__ __launch_bounds__(256) void k_wcvt(const float* __restrict__ w0,
                                              const float* __restrict__ w1,
                                              u16* __restrict__ Wbf){
    int s = blockIdx.y;
    const float* w = s ? w1 : w0;
    u16* o = Wbf + (size_t)s * (O3 * C_);
    int idx = (blockIdx.x * 256 + threadIdx.x) * 4;
    float4 v = *reinterpret_cast<const float4*>(&w[idx]);
    o[idx+0] = f2bf(v.x); o[idx+1] = f2bf(v.y);
    o[idx+2] = f2bf(v.z); o[idx+3] = f2bf(v.w);
}

// K0b: w_eff^T[s][oc][hc] = sum_head out_w_s[head*HID+hc][oc]  (heads identical)
// one output per thread; lanes span oc (coalesced within each head read)
__global__ __launch_bounds__(256) void k_weff(const float* __restrict__ w0,
                                              const float* __restrict__ w1,
                                              u16* __restrict__ weff){
    int gid = blockIdx.x * 256 + threadIdx.x;   // 2*128*256 = 65536
    int oc = gid & 255, hc = (gid >> 8) & 127, s = gid >> 15;
    const float* w = s ? w1 : w0;
    float acc = 0.f;
    #pragma unroll
    for (int h = 0; h < NH; ++h) acc += w[(h*HID + hc)*C_ + oc];
    weff[(s*C_ + oc)*HID + hc] = f2bf(acc);
}

// ---------------------------------------------------------------------------
// K1a: transpose+convert X[bs][c][n] fp32 -> Xt[bs][n][c] bf16 (Xt in d_out)
__global__ __launch_bounds__(256) void k_transpose(const float* __restrict__ x0,
                                                   const float* __restrict__ x1,
                                                   u16* __restrict__ Xt){
    __shared__ __align__(16) u16 tile[64][72];
    int z = blockIdx.z, b = z >> 1, s = z & 1;
    const float* X = (s ? x1 : x0) + (size_t)b * (C_ * N_);
    u16* out = Xt + (size_t)z * (N_ * C_);
    int n0 = blockIdx.x * 64, c0 = blockIdx.y * 64;
    int t = threadIdx.x;
    int lr = t >> 4, lc = (t & 15) * 4;
    #pragma unroll
    for (int rep = 0; rep < 4; ++rep){
        int c = lr + rep * 16;
        float4 v = *reinterpret_cast<const float4*>(&X[(size_t)(c0 + c) * N_ + n0 + lc]);
        tile[c][lc+0] = f2bf(v.x); tile[c][lc+1] = f2bf(v.y);
        tile[c][lc+2] = f2bf(v.z); tile[c][lc+3] = f2bf(v.w);
    }
    __syncthreads();
    int row = t >> 3, col8 = (t & 7) * 8;
    #pragma unroll
    for (int rep = 0; rep < 2; ++rep){
        int n = row + rep * 32;
        u16x8 v;
        #pragma unroll
        for (int j = 0; j < 8; ++j) v[j] = tile[col8 + j][n];
        *reinterpret_cast<u16x8*>(&out[(size_t)(n0 + n) * C_ + c0 + col8]) = v;
    }
}

// ---------------------------------------------------------------------------
// K1b: embed GEMM.  Q is PRE-SCALED by QPRE so attention uses exp2 directly.
__global__ __launch_bounds__(256, 4) void k_embed(const u16* __restrict__ Xt,
        const u16* __restrict__ Wbf,
        const float* __restrict__ b0, const float* __restrict__ b1,
        u16* __restrict__ Qt, u16* __restrict__ Kt, u16* __restrict__ Vl){
    int z = blockIdx.z, s = z & 1;
    const u16* W = Wbf + (size_t)s * (O3 * C_);
    const float* bias = s ? b1 : b0;
    const u16* Xb = Xt + (size_t)z * (N_ * C_);
    int lane = threadIdx.x & 63, wave = threadIdx.x >> 6;
    int l16 = lane & 15, quad = lane >> 4;
    int o0 = blockIdx.y * 64 + wave * 16;
    int n0 = blockIdx.x * 64;
    f4 acc[4] = {f4{0,0,0,0}, f4{0,0,0,0}, f4{0,0,0,0}, f4{0,0,0,0}};
    #pragma unroll
    for (int kk = 0; kk < 8; ++kk){           // K = 256 = 8 * 32
        bf8 a = *reinterpret_cast<const bf8*>(&W[(o0 + l16) * C_ + kk*32 + quad*8]);
        #pragma unroll
        for (int nt = 0; nt < 4; ++nt){
            bf8 bb = *reinterpret_cast<const bf8*>(&Xb[(size_t)(n0 + nt*16 + l16) * C_ + kk*32 + quad*8]);
            acc[nt] = MFMA(a, bb, acc[nt]);
        }
    }
    #pragma unroll
    for (int nt = 0; nt < 4; ++nt){
        int n = n0 + nt*16 + l16;
        #pragma unroll
        for (int r = 0; r < 4; ++r){
            int o = o0 + quad*4 + r;
            float e = acc[nt][r] + bias[o];
            if (o < HID)            Qt[((size_t)z*N_ + n)*HID + o] = f2bf(e * QPRE);
            else if (o < 2*HID)     Kt[((size_t)z*N_ + n)*HID + (o - HID)] = f2bf(e);
            else                    Vl[((size_t)z*HID + (o - 2*HID))*N_ + n] = f2bf(e);
        }
    }
}

// ---------------------------------------------------------------------------
// K2 (fused): max-free flash attention + output projection + residual.
//   p = exp2(q_pre . k); rowsum via MFMA w/ ones-B (lane-local normalize).
//   K reg-double-buffered, V early, per-wave P LDS double-buffer,
//   XCD-swizzled blockIdx, 4 blocks/CU (all 576 blocks co-resident).
__global__ __launch_bounds__(256, 4) void k_attn_out(const u16* __restrict__ Qt,
        const u16* __restrict__ Kt, const u16* __restrict__ Vl,
        const u16* __restrict__ weff,
        const float* __restrict__ ob0, const float* __restrict__ ob1,
        const float* __restrict__ x0, const float* __restrict__ x1,
        float* __restrict__ out){
    // smem: in-loop = per-wave double-buffered P tiles (wave w, buf q at
    //       (w*2+q)*16*72); post-loop = H tile [64][136] (8704 u16).
    __shared__ __align__(16) u16 smem[8 * 16 * 72];   // 18432 B
    int bx = blockIdx.x;                      // 576 = 8 XCD * 72
    int xcd = bx & 7, t = bx >> 3;
    int z  = xcd*2 + (t >= 36 ? 1 : 0);       // XCD x serves z in {2x,2x+1}
    int mt = (t >= 36) ? (t - 36) : t;
    int b = z >> 1, s = z & 1;
    const u16* Q = Qt + (size_t)(b*2 + (1 - s)) * (N_ * HID);
    const u16* K = Kt + (size_t)(b*2 + s)       * (N_ * HID);
    const u16* V = Vl + (size_t)(b*2 + s)       * ((size_t)HID * N_);
    const u16* Wf   = weff + (size_t)s * (C_ * HID);
    const float* bias = s ? ob1 : ob0;
    const float* X = (s ? x1 : x0) + (size_t)b * (C_ * N_);
    float* O = out + (size_t)s * ((size_t)B_ * C_ * N_) + (size_t)b * (C_ * N_);
    int lane = threadIdx.x & 63, wave = threadIdx.x >> 6;
    int l16 = lane & 15, quad = lane >> 4;
    int m0 = mt * 64 + wave * 16;

    bf8 aq[4];
    #pragma unroll
    for (int kk = 0; kk < 4; ++kk)
        aq[kk] = *reinterpret_cast<const bf8*>(&Q[(size_t)(m0 + l16)*HID + kk*32 + quad*8]);

    bf8 ones;
    #pragma unroll
    for (int j = 0; j < 8; ++j) ones[j] = (short)0x3F80;   // bf16 1.0

    f4 oacc[8];
    #pragma unroll
    for (int ct = 0; ct < 8; ++ct) oacc[ct] = f4{0,0,0,0};
    f4 sumacc = f4{0,0,0,0};

    bf8 kfa[16], kfb[16];
    #pragma unroll
    for (int kk = 0; kk < 4; ++kk)
        #pragma unroll
        for (int nt = 0; nt < 4; ++nt)
            kfa[kk*4+nt] = *reinterpret_cast<const bf8*>(&K[(size_t)(nt*16 + l16)*HID + kk*32 + quad*8]);

    auto chunk = [&](bf8 (&kcur)[16], bf8 (&knext)[16], int n0, bool prefetch, int pb){
        u16* pw = smem + (wave*2 + pb) * (16*72);
        // V group 0 early (consumed after softmax, ~300 cyc later)
        bf8 vf0[8], vf1[8];
        #pragma unroll
        for (int ct = 0; ct < 8; ++ct)
            vf0[ct] = *reinterpret_cast<const bf8*>(&V[(size_t)(ct*16 + l16)*N_ + n0 + quad*8]);
        // QK
        f4 sacc[4] = {f4{0,0,0,0}, f4{0,0,0,0}, f4{0,0,0,0}, f4{0,0,0,0}};
        #pragma unroll
        for (int kk = 0; kk < 4; ++kk)
            #pragma unroll
            for (int nt = 0; nt < 4; ++nt)
                sacc[nt] = MFMA(aq[kk], kcur[kk*4+nt], sacc[nt]);
        // prefetch next chunk's K (kcur now dead)
        if (prefetch){
            #pragma unroll
            for (int kk = 0; kk < 4; ++kk)
                #pragma unroll
                for (int nt = 0; nt < 4; ++nt)
                    knext[kk*4+nt] = *reinterpret_cast<const bf8*>(&K[(size_t)(n0 + 64 + nt*16 + l16)*HID + kk*32 + quad*8]);
        }
        // V group 1
        #pragma unroll
        for (int ct = 0; ct < 8; ++ct)
            vf1[ct] = *reinterpret_cast<const bf8*>(&V[(size_t)(ct*16 + l16)*N_ + n0 + 32 + quad*8]);
        // p = exp2(s), truncating bf16 store to per-wave LDS
        #pragma unroll
        for (int nt = 0; nt < 4; ++nt)
            #pragma unroll
            for (int r = 0; r < 4; ++r)
                pw[(quad*4 + r)*72 + nt*16 + l16] = hi16(fexp2(sacc[nt][r]));
        // PV + rowsum (kk2 = 0 then 1)
        {
            bf8 ap = *reinterpret_cast<const bf8*>(&pw[l16*72 + quad*8]);
            sumacc = MFMA(ap, ones, sumacc);
            #pragma unroll
            for (int ct = 0; ct < 8; ++ct) oacc[ct] = MFMA(ap, vf0[ct], oacc[ct]);
        }
        {
            bf8 ap = *reinterpret_cast<const bf8*>(&pw[l16*72 + 32 + quad*8]);
            sumacc = MFMA(ap, ones, sumacc);
            #pragma unroll
            for (int ct = 0; ct < 8; ++ct) oacc[ct] = MFMA(ap, vf1[ct], oacc[ct]);
        }
    };

    for (int nc = 0; nc < N_/64; nc += 2){
        chunk(kfa, kfb, nc*64,        true,              0);
        chunk(kfb, kfa, nc*64 + 64,   nc + 2 < N_/64,    1);
    }

    // normalize (lane-local: sumacc has identical C-layout) and stash H
    __syncthreads();                           // P region dead in all waves
    float inv[4];
    #pragma unroll
    for (int r = 0; r < 4; ++r) inv[r] = 1.0f / sumacc[r];
    #pragma unroll
    for (int ct = 0; ct < 8; ++ct)
        #pragma unroll
        for (int r = 0; r < 4; ++r)
            smem[(wave*16 + quad*4 + r)*136 + ct*16 + l16] = f2bf(oacc[ct][r] * inv[r]);
    __syncthreads();

    // out GEMM: wave w -> oc [w*64, w*64+64); K = HID = 128
    int mb = mt * 64;
    int oc0 = wave * 64;
    f4 acc2[4][4];
    #pragma unroll
    for (int ot = 0; ot < 4; ++ot)
        #pragma unroll
        for (int nt = 0; nt < 4; ++nt) acc2[ot][nt] = f4{0,0,0,0};
    #pragma unroll
    for (int kk = 0; kk < 4; ++kk){
        bf8 bh[4];
        #pragma unroll
        for (int nt = 0; nt < 4; ++nt)
            bh[nt] = *reinterpret_cast<const bf8*>(&smem[(nt*16 + l16)*136 + kk*32 + quad*8]);
        #pragma unroll
        for (int ot = 0; ot < 4; ++ot){
            bf8 a = *reinterpret_cast<const bf8*>(&Wf[(oc0 + ot*16 + l16)*HID + kk*32 + quad*8]);
            #pragma unroll
            for (int nt = 0; nt < 4; ++nt)
                acc2[ot][nt] = MFMA(a, bh[nt], acc2[ot][nt]);
        }
    }
    #pragma unroll
    for (int ot = 0; ot < 4; ++ot)
        #pragma unroll
        for (int nt = 0; nt < 4; ++nt){
            int m = mb + nt*16 + l16;
            #pragma unroll
            for (int r = 0; r < 4; ++r){
                int oc = oc0 + ot*16 + quad*4 + r;
                O[(size_t)oc*N_ + m] = acc2[ot][nt][r] + bias[oc] + X[(size_t)oc*N_ + m];
            }
        }
}

// ---------------------------------------------------------------------------
extern "C" void kernel_launch(void* const* d_in, const int* in_sizes, int n_in,
                              void* d_out, int out_size, void* d_ws, size_t ws_size,
                              hipStream_t stream){
    const float* x0  = (const float*)d_in[0];
    const float* x1  = (const float*)d_in[1];
    const float* ew0 = (const float*)d_in[2];
    const float* eb0 = (const float*)d_in[3];
    const float* ew1 = (const float*)d_in[4];
    const float* eb1 = (const float*)d_in[5];
    const float* ow0 = (const float*)d_in[6];
    const float* ob0 = (const float*)d_in[7];
    const float* ow1 = (const float*)d_in[8];
    const float* ob1 = (const float*)d_in[9];

    u16* ws = (u16*)d_ws;
    const size_t QT_E = (size_t)16 * N_ * HID;
    u16* Qt   = ws;
    u16* Kt   = Qt + QT_E;
    u16* Vl   = Kt + QT_E;
    u16* Wbf  = Vl + QT_E;
    u16* weff = Wbf + (size_t)2 * O3 * C_;
    u16* Xt   = (u16*)d_out;                  // scratch phase

    k_wcvt     <<<dim3(96, 2),     dim3(256), 0, stream>>>(ew0, ew1, Wbf);
    k_weff     <<<dim3(256),       dim3(256), 0, stream>>>(ow0, ow1, weff);
    k_transpose<<<dim3(36, 4, 16), dim3(256), 0, stream>>>(x0, x1, Xt);
    k_embed    <<<dim3(36, 6, 16), dim3(256), 0, stream>>>(Xt, Wbf, eb0, eb1, Qt, Kt, Vl);
    k_attn_out <<<dim3(576),       dim3(256), 0, stream>>>(Qt, Kt, Vl, weff, ob0, ob1,
                                                           x0, x1, (float*)d_out);
}

// Round 6
// 311.855 us; speedup vs baseline: 2.2215x; 2.2215x over previous
//
#include <hip/hip_runtime.h>
#include <stdint.h>

// Problem constants
#define B_   8
#define C_   256
#define N_   2304          // 48*48 spatial
#define HID  128
#define O3   384           // 3*HID
#define NH   4
#define SCALE 0.0625f      // 256^-0.5
#define QPRE 0.09016844f   // SCALE * log2(e): q pre-scale so p = exp2(q.k)

typedef unsigned short u16;
typedef short  bf8  __attribute__((ext_vector_type(8)));   // 8 bf16 (4 VGPRs) MFMA A/B frag
typedef float  f4   __attribute__((ext_vector_type(4)));   // MFMA C/D frag
typedef u16    u16x8 __attribute__((ext_vector_type(8)));

#define MFMA(a,b,c) __builtin_amdgcn_mfma_f32_16x16x32_bf16((a),(b),(c),0,0,0)

static __device__ __forceinline__ u16 f2bf(float f){
    union { float f; unsigned int i; } v; v.f = f;
    unsigned int r = v.i + 0x7FFFu + ((v.i >> 16) & 1u);   // round-to-nearest-even
    return (u16)(r >> 16);
}
static __device__ __forceinline__ float fexp2(float x){
#if __has_builtin(__builtin_amdgcn_exp2f)
    return __builtin_amdgcn_exp2f(x);
#else
    return __expf(x * 0.69314718f);
#endif
}
static __device__ __forceinline__ u16 hi16(float f){       // truncating f32->bf16
    union { float f; unsigned int i; } v; v.f = f;
    return (u16)(v.i >> 16);
}
// async global->LDS DMA, 16B per lane; lptr must be wave-uniform (lane l
// lands at lptr + l*16). No VGPR cost for the data.
static __device__ __forceinline__ void dma16(const void* g, void* l){
    __builtin_amdgcn_global_load_lds(
        (const __attribute__((address_space(1))) void*)g,
        (__attribute__((address_space(3))) void*)l, 16, 0, 0);
}

// ---------------------------------------------------------------------------
// K0a: convert embed weights fp32 -> bf16.
__global__ __launch_bounds__(256) void k_wcvt(const float* __restrict__ w0,
                                              const float* __restrict__ w1,
                                              u16* __restrict__ Wbf){
    int s = blockIdx.y;
    const float* w = s ? w1 : w0;
    u16* o = Wbf + (size_t)s * (O3 * C_);
    int idx = (blockIdx.x * 256 + threadIdx.x) * 4;
    float4 v = *reinterpret_cast<const float4*>(&w[idx]);
    o[idx+0] = f2bf(v.x); o[idx+1] = f2bf(v.y);
    o[idx+2] = f2bf(v.z); o[idx+3] = f2bf(v.w);
}

// K0b: w_eff^T[s][oc][hc] = sum_head out_w_s[head*HID+hc][oc]  (heads identical)
__global__ __launch_bounds__(256) void k_weff(const float* __restrict__ w0,
                                              const float* __restrict__ w1,
                                              u16* __restrict__ weff){
    int gid = blockIdx.x * 256 + threadIdx.x;   // 2*128*256 = 65536
    int oc = gid & 255, hc = (gid >> 8) & 127, s = gid >> 15;
    const float* w = s ? w1 : w0;
    float acc = 0.f;
    #pragma unroll
    for (int h = 0; h < NH; ++h) acc += w[(h*HID + hc)*C_ + oc];
    weff[(s*C_ + oc)*HID + hc] = f2bf(acc);
}

// ---------------------------------------------------------------------------
// K1a: transpose+convert X[bs][c][n] fp32 -> Xt[bs][n][c] bf16 (Xt in d_out)
__global__ __launch_bounds__(256) void k_transpose(const float* __restrict__ x0,
                                                   const float* __restrict__ x1,
                                                   u16* __restrict__ Xt){
    __shared__ __align__(16) u16 tile[64][72];
    int z = blockIdx.z, b = z >> 1, s = z & 1;
    const float* X = (s ? x1 : x0) + (size_t)b * (C_ * N_);
    u16* out = Xt + (size_t)z * (N_ * C_);
    int n0 = blockIdx.x * 64, c0 = blockIdx.y * 64;
    int t = threadIdx.x;
    int lr = t >> 4, lc = (t & 15) * 4;
    #pragma unroll
    for (int rep = 0; rep < 4; ++rep){
        int c = lr + rep * 16;
        float4 v = *reinterpret_cast<const float4*>(&X[(size_t)(c0 + c) * N_ + n0 + lc]);
        tile[c][lc+0] = f2bf(v.x); tile[c][lc+1] = f2bf(v.y);
        tile[c][lc+2] = f2bf(v.z); tile[c][lc+3] = f2bf(v.w);
    }
    __syncthreads();
    int row = t >> 3, col8 = (t & 7) * 8;
    #pragma unroll
    for (int rep = 0; rep < 2; ++rep){
        int n = row + rep * 32;
        u16x8 v;
        #pragma unroll
        for (int j = 0; j < 8; ++j) v[j] = tile[col8 + j][n];
        *reinterpret_cast<u16x8*>(&out[(size_t)(n0 + n) * C_ + c0 + col8]) = v;
    }
}

// ---------------------------------------------------------------------------
// K1b: embed GEMM.  Q is PRE-SCALED by QPRE so attention uses exp2 directly.
__global__ __launch_bounds__(256, 4) void k_embed(const u16* __restrict__ Xt,
        const u16* __restrict__ Wbf,
        const float* __restrict__ b0, const float* __restrict__ b1,
        u16* __restrict__ Qt, u16* __restrict__ Kt, u16* __restrict__ Vl){
    int z = blockIdx.z, s = z & 1;
    const u16* W = Wbf + (size_t)s * (O3 * C_);
    const float* bias = s ? b1 : b0;
    const u16* Xb = Xt + (size_t)z * (N_ * C_);
    int lane = threadIdx.x & 63, wave = threadIdx.x >> 6;
    int l16 = lane & 15, quad = lane >> 4;
    int o0 = blockIdx.y * 64 + wave * 16;
    int n0 = blockIdx.x * 64;
    f4 acc[4] = {f4{0,0,0,0}, f4{0,0,0,0}, f4{0,0,0,0}, f4{0,0,0,0}};
    #pragma unroll
    for (int kk = 0; kk < 8; ++kk){           // K = 256 = 8 * 32
        bf8 a = *reinterpret_cast<const bf8*>(&W[(o0 + l16) * C_ + kk*32 + quad*8]);
        #pragma unroll
        for (int nt = 0; nt < 4; ++nt){
            bf8 bb = *reinterpret_cast<const bf8*>(&Xb[(size_t)(n0 + nt*16 + l16) * C_ + kk*32 + quad*8]);
            acc[nt] = MFMA(a, bb, acc[nt]);
        }
    }
    #pragma unroll
    for (int nt = 0; nt < 4; ++nt){
        int n = n0 + nt*16 + l16;
        #pragma unroll
        for (int r = 0; r < 4; ++r){
            int o = o0 + quad*4 + r;
            float e = acc[nt][r] + bias[o];
            if (o < HID)            Qt[((size_t)z*N_ + n)*HID + o] = f2bf(e * QPRE);
            else if (o < 2*HID)     Kt[((size_t)z*N_ + n)*HID + (o - HID)] = f2bf(e);
            else                    Vl[((size_t)z*HID + (o - 2*HID))*N_ + n] = f2bf(e);
        }
    }
}

// ---------------------------------------------------------------------------
// K2 (fused): max-free flash attention + output projection + residual.
//   K/V tiles staged into LDS per 64-key chunk via global_load_lds DMA
//   (no VGPR cost -> full memory-level parallelism, no spills).
//   LDS chunk-interleaved layout: 16B chunk c of K at kbuf+ (cc*64+n)*16B,
//   matching both the DMA lane mapping and the MFMA fragment reads.
__global__ __launch_bounds__(256, 2) void k_attn_out(const u16* __restrict__ Qt,
        const u16* __restrict__ Kt, const u16* __restrict__ Vl,
        const u16* __restrict__ weff,
        const float* __restrict__ ob0, const float* __restrict__ ob1,
        const float* __restrict__ x0, const float* __restrict__ x1,
        float* __restrict__ out){
    __shared__ __align__(16) u16 kbuf[64*128];      // 16 KB: chunk (cc,n) at (cc*64+n)*8
    __shared__ __align__(16) u16 vbuf[64*128];      // 16 KB: chunk (nc,hc) at (nc*128+hc)*8
    __shared__ __align__(16) u16 smem[8*16*72];     // P tiles (dbuf/wave) ; H tile in epilogue
    int bx = blockIdx.x;                      // 576 = 8 XCD * 72
    int xcd = bx & 7, t = bx >> 3;
    int z  = xcd*2 + (t >= 36 ? 1 : 0);       // XCD x serves z in {2x,2x+1}
    int mt = (t >= 36) ? (t - 36) : t;
    int b = z >> 1, s = z & 1;
    const u16* Q = Qt + (size_t)(b*2 + (1 - s)) * (N_ * HID);
    const u16* K = Kt + (size_t)(b*2 + s)       * (N_ * HID);
    const u16* V = Vl + (size_t)(b*2 + s)       * ((size_t)HID * N_);
    const u16* Wf   = weff + (size_t)s * (C_ * HID);
    const float* bias = s ? ob1 : ob0;
    const float* X = (s ? x1 : x0) + (size_t)b * (C_ * N_);
    float* O = out + (size_t)s * ((size_t)B_ * C_ * N_) + (size_t)b * (C_ * N_);
    int lane = threadIdx.x & 63, wave = threadIdx.x >> 6;
    int l16 = lane & 15, quad = lane >> 4;
    int m0 = mt * 64 + wave * 16;

    bf8 aq[4];
    #pragma unroll
    for (int kk = 0; kk < 4; ++kk)
        aq[kk] = *reinterpret_cast<const bf8*>(&Q[(size_t)(m0 + l16)*HID + kk*32 + quad*8]);

    bf8 ones;
    #pragma unroll
    for (int j = 0; j < 8; ++j) ones[j] = (short)0x3F80;   // bf16 1.0

    f4 oacc[8];
    #pragma unroll
    for (int ct = 0; ct < 8; ++ct) oacc[ct] = f4{0,0,0,0};
    f4 sumacc = f4{0,0,0,0};

    const char* Kb = (const char*)K;
    const char* Vb = (const char*)V;

    for (int nc = 0; nc < N_/64; ++nc){
        int n0 = nc * 64;
        __syncthreads();                      // previous chunk's LDS reads done
        // stage K tile: issue ik covers channel-chunk cc=ik, rows n=lane
        #pragma unroll
        for (int j = 0; j < 4; ++j){
            int ik = wave*4 + j;
            dma16(Kb + ((size_t)(n0 + lane)*HID + ik*8)*2, &kbuf[ik*64*8]);
        }
        // stage V tile: issue iv covers n-chunk nc2=iv>>1, hc = (iv&1)*64+lane
        #pragma unroll
        for (int j = 0; j < 4; ++j){
            int iv = wave*4 + j;
            dma16(Vb + ((size_t)((iv&1)*64 + lane)*N_ + n0 + (iv>>1)*8)*2,
                  &vbuf[iv*64*8]);
        }
        __syncthreads();                      // drains vmcnt(0): tiles visible
        // QK
        f4 sacc[4] = {f4{0,0,0,0}, f4{0,0,0,0}, f4{0,0,0,0}, f4{0,0,0,0}};
        #pragma unroll
        for (int kk = 0; kk < 4; ++kk)
            #pragma unroll
            for (int nt = 0; nt < 4; ++nt){
                bf8 bk = *reinterpret_cast<const bf8*>(&kbuf[((kk*4+quad)*64 + nt*16 + l16)*8]);
                sacc[nt] = MFMA(aq[kk], bk, sacc[nt]);
            }
        // p = exp2(s), truncating bf16 store to per-wave LDS (double-buffered)
        u16* pw = smem + (wave*2 + (nc & 1)) * (16*72);
        #pragma unroll
        for (int nt = 0; nt < 4; ++nt)
            #pragma unroll
            for (int r = 0; r < 4; ++r)
                pw[(quad*4 + r)*72 + nt*16 + l16] = hi16(fexp2(sacc[nt][r]));
        // PV + rowsum
        #pragma unroll
        for (int kk2 = 0; kk2 < 2; ++kk2){
            bf8 ap = *reinterpret_cast<const bf8*>(&pw[l16*72 + kk2*32 + quad*8]);
            sumacc = MFMA(ap, ones, sumacc);
            #pragma unroll
            for (int ct = 0; ct < 8; ++ct){
                bf8 bv = *reinterpret_cast<const bf8*>(&vbuf[((kk2*4+quad)*128 + ct*16 + l16)*8]);
                oacc[ct] = MFMA(ap, bv, oacc[ct]);
            }
        }
    }

    // normalize (lane-local: sumacc has same C-layout as oacc) and stash H
    __syncthreads();                           // P region dead in all waves
    float inv[4];
    #pragma unroll
    for (int r = 0; r < 4; ++r) inv[r] = 1.0f / sumacc[r];
    #pragma unroll
    for (int ct = 0; ct < 8; ++ct)
        #pragma unroll
        for (int r = 0; r < 4; ++r)
            smem[(wave*16 + quad*4 + r)*136 + ct*16 + l16] = f2bf(oacc[ct][r] * inv[r]);
    __syncthreads();

    // out GEMM: wave w -> oc [w*64, w*64+64); K = HID = 128
    int mb = mt * 64;
    int oc0 = wave * 64;
    f4 acc2[4][4];
    #pragma unroll
    for (int ot = 0; ot < 4; ++ot)
        #pragma unroll
        for (int nt = 0; nt < 4; ++nt) acc2[ot][nt] = f4{0,0,0,0};
    #pragma unroll
    for (int kk = 0; kk < 4; ++kk){
        bf8 bh[4];
        #pragma unroll
        for (int nt = 0; nt < 4; ++nt)
            bh[nt] = *reinterpret_cast<const bf8*>(&smem[(nt*16 + l16)*136 + kk*32 + quad*8]);
        #pragma unroll
        for (int ot = 0; ot < 4; ++ot){
            bf8 a = *reinterpret_cast<const bf8*>(&Wf[(oc0 + ot*16 + l16)*HID + kk*32 + quad*8]);
            #pragma unroll
            for (int nt = 0; nt < 4; ++nt)
                acc2[ot][nt] = MFMA(a, bh[nt], acc2[ot][nt]);
        }
    }
    #pragma unroll
    for (int ot = 0; ot < 4; ++ot)
        #pragma unroll
        for (int nt = 0; nt < 4; ++nt){
            int m = mb + nt*16 + l16;
            #pragma unroll
            for (int r = 0; r < 4; ++r){
                int oc = oc0 + ot*16 + quad*4 + r;
                O[(size_t)oc*N_ + m] = acc2[ot][nt][r] + bias[oc] + X[(size_t)oc*N_ + m];
            }
        }
}

// ---------------------------------------------------------------------------
extern "C" void kernel_launch(void* const* d_in, const int* in_sizes, int n_in,
                              void* d_out, int out_size, void* d_ws, size_t ws_size,
                              hipStream_t stream){
    const float* x0  = (const float*)d_in[0];
    const float* x1  = (const float*)d_in[1];
    const float* ew0 = (const float*)d_in[2];
    const float* eb0 = (const float*)d_in[3];
    const float* ew1 = (const float*)d_in[4];
    const float* eb1 = (const float*)d_in[5];
    const float* ow0 = (const float*)d_in[6];
    const float* ob0 = (const float*)d_in[7];
    const float* ow1 = (const float*)d_in[8];
    const float* ob1 = (const float*)d_in[9];

    u16* ws = (u16*)d_ws;
    const size_t QT_E = (size_t)16 * N_ * HID;
    u16* Qt   = ws;
    u16* Kt   = Qt + QT_E;
    u16* Vl   = Kt + QT_E;
    u16* Wbf  = Vl + QT_E;
    u16* weff = Wbf + (size_t)2 * O3 * C_;
    u16* Xt   = (u16*)d_out;                  // scratch phase

    k_wcvt     <<<dim3(96, 2),     dim3(256), 0, stream>>>(ew0, ew1, Wbf);
    k_weff     <<<dim3(256),       dim3(256), 0, stream>>>(ow0, ow1, weff);
    k_transpose<<<dim3(36, 4, 16), dim3(256), 0, stream>>>(x0, x1, Xt);
    k_embed    <<<dim3(36, 6, 16), dim3(256), 0, stream>>>(Xt, Wbf, eb0, eb1, Qt, Kt, Vl);
    k_attn_out <<<dim3(576),       dim3(256), 0, stream>>>(Qt, Kt, Vl, weff, ob0, ob1,
                                                           x0, x1, (float*)d_out);
}

// Round 7
// 266.319 us; speedup vs baseline: 2.6014x; 1.1710x over previous
//
#include <hip/hip_runtime.h>
#include <stdint.h>

// Problem constants
#define B_   8
#define C_   256
#define N_   2304          // 48*48 spatial
#define HID  128
#define O3   384           // 3*HID
#define NH   4
#define SCALE 0.0625f      // 256^-0.5
#define QPRE 0.09016844f   // SCALE * log2(e): q pre-scale so p = exp2(q.k)

typedef unsigned short u16;
typedef short  bf8  __attribute__((ext_vector_type(8)));   // 8 bf16 (4 VGPRs) MFMA A/B frag
typedef float  f4   __attribute__((ext_vector_type(4)));   // MFMA C/D frag
typedef u16    u16x8 __attribute__((ext_vector_type(8)));

#define MFMA(a,b,c) __builtin_amdgcn_mfma_f32_16x16x32_bf16((a),(b),(c),0,0,0)

static __device__ __forceinline__ u16 f2bf(float f){
    union { float f; unsigned int i; } v; v.f = f;
    unsigned int r = v.i + 0x7FFFu + ((v.i >> 16) & 1u);   // round-to-nearest-even
    return (u16)(r >> 16);
}
static __device__ __forceinline__ float fexp2(float x){
#if __has_builtin(__builtin_amdgcn_exp2f)
    return __builtin_amdgcn_exp2f(x);
#else
    return __expf(x * 0.69314718f);
#endif
}
static __device__ __forceinline__ u16 hi16(float f){       // truncating f32->bf16
    union { float f; unsigned int i; } v; v.f = f;
    return (u16)(v.i >> 16);
}
// async global->LDS DMA, 16B per lane; both sides contiguous per lane now.
static __device__ __forceinline__ void dma16(const void* g, void* l){
    __builtin_amdgcn_global_load_lds(
        (const __attribute__((address_space(1))) void*)g,
        (__attribute__((address_space(3))) void*)l, 16, 0, 0);
}

// ---------------------------------------------------------------------------
// K0a: convert embed weights fp32 -> bf16.
__global__ __launch_bounds__(256) void k_wcvt(const float* __restrict__ w0,
                                              const float* __restrict__ w1,
                                              u16* __restrict__ Wbf){
    int s = blockIdx.y;
    const float* w = s ? w1 : w0;
    u16* o = Wbf + (size_t)s * (O3 * C_);
    int idx = (blockIdx.x * 256 + threadIdx.x) * 4;
    float4 v = *reinterpret_cast<const float4*>(&w[idx]);
    o[idx+0] = f2bf(v.x); o[idx+1] = f2bf(v.y);
    o[idx+2] = f2bf(v.z); o[idx+3] = f2bf(v.w);
}

// K0b: w_eff^T[s][oc][hc] = sum_head out_w_s[head*HID+hc][oc]  (heads identical)
__global__ __launch_bounds__(256) void k_weff(const float* __restrict__ w0,
                                              const float* __restrict__ w1,
                                              u16* __restrict__ weff){
    int gid = blockIdx.x * 256 + threadIdx.x;   // 2*128*256 = 65536
    int oc = gid & 255, hc = (gid >> 8) & 127, s = gid >> 15;
    const float* w = s ? w1 : w0;
    float acc = 0.f;
    #pragma unroll
    for (int h = 0; h < NH; ++h) acc += w[(h*HID + hc)*C_ + oc];
    weff[(s*C_ + oc)*HID + hc] = f2bf(acc);
}

// ---------------------------------------------------------------------------
// K1a: transpose+convert X[bs][c][n] fp32 -> Xt[bs][n][c] bf16 (Xt in d_out)
__global__ __launch_bounds__(256) void k_transpose(const float* __restrict__ x0,
                                                   const float* __restrict__ x1,
                                                   u16* __restrict__ Xt){
    __shared__ __align__(16) u16 tile[64][72];
    int z = blockIdx.z, b = z >> 1, s = z & 1;
    const float* X = (s ? x1 : x0) + (size_t)b * (C_ * N_);
    u16* out = Xt + (size_t)z * (N_ * C_);
    int n0 = blockIdx.x * 64, c0 = blockIdx.y * 64;
    int t = threadIdx.x;
    int lr = t >> 4, lc = (t & 15) * 4;
    #pragma unroll
    for (int rep = 0; rep < 4; ++rep){
        int c = lr + rep * 16;
        float4 v = *reinterpret_cast<const float4*>(&X[(size_t)(c0 + c) * N_ + n0 + lc]);
        tile[c][lc+0] = f2bf(v.x); tile[c][lc+1] = f2bf(v.y);
        tile[c][lc+2] = f2bf(v.z); tile[c][lc+3] = f2bf(v.w);
    }
    __syncthreads();
    int row = t >> 3, col8 = (t & 7) * 8;
    #pragma unroll
    for (int rep = 0; rep < 2; ++rep){
        int n = row + rep * 32;
        u16x8 v;
        #pragma unroll
        for (int j = 0; j < 8; ++j) v[j] = tile[col8 + j][n];
        *reinterpret_cast<u16x8*>(&out[(size_t)(n0 + n) * C_ + c0 + col8]) = v;
    }
}

// ---------------------------------------------------------------------------
// K1b: embed GEMM.  Q pre-scaled by QPRE.  K/V written in DMA-friendly
// chunk-interleaved layouts:
//   Kc[z][nc][cc][n&63][8] : elem (n,h) at ((n>>6)*16 + (h>>3))*512 + (n&63)*8 + (h&7)
//   Vc[z][nc][pc][hc][8]   : elem (hc,n) at ((n>>6)*8 + ((n>>3)&7))*1024 + hc*8 + (n&7)
__global__ __launch_bounds__(256, 4) void k_embed(const u16* __restrict__ Xt,
        const u16* __restrict__ Wbf,
        const float* __restrict__ b0, const float* __restrict__ b1,
        u16* __restrict__ Qt, u16* __restrict__ Kc, u16* __restrict__ Vc){
    int z = blockIdx.z, s = z & 1;
    const u16* W = Wbf + (size_t)s * (O3 * C_);
    const float* bias = s ? b1 : b0;
    const u16* Xb = Xt + (size_t)z * (N_ * C_);
    int lane = threadIdx.x & 63, wave = threadIdx.x >> 6;
    int l16 = lane & 15, quad = lane >> 4;
    int o0 = blockIdx.y * 64 + wave * 16;
    int n0 = blockIdx.x * 64;
    f4 acc[4] = {f4{0,0,0,0}, f4{0,0,0,0}, f4{0,0,0,0}, f4{0,0,0,0}};
    #pragma unroll
    for (int kk = 0; kk < 8; ++kk){           // K = 256 = 8 * 32
        bf8 a = *reinterpret_cast<const bf8*>(&W[(o0 + l16) * C_ + kk*32 + quad*8]);
        #pragma unroll
        for (int nt = 0; nt < 4; ++nt){
            bf8 bb = *reinterpret_cast<const bf8*>(&Xb[(size_t)(n0 + nt*16 + l16) * C_ + kk*32 + quad*8]);
            acc[nt] = MFMA(a, bb, acc[nt]);
        }
    }
    size_t zq = (size_t)z * (N_ * HID);
    #pragma unroll
    for (int nt = 0; nt < 4; ++nt){
        int n = n0 + nt*16 + l16;
        #pragma unroll
        for (int r = 0; r < 4; ++r){
            int o = o0 + quad*4 + r;
            float e = acc[nt][r] + bias[o];
            if (o < HID){
                Qt[zq + (size_t)n*HID + o] = f2bf(e * QPRE);
            } else if (o < 2*HID){
                int h = o - HID;
                Kc[zq + ((n>>6)*16 + (h>>3))*512 + ((n&63)<<3) + (h&7)] = f2bf(e);
            } else {
                int hc = o - 2*HID;
                Vc[zq + ((n>>6)*8 + ((n>>3)&7))*1024 + (hc<<3) + (n&7)] = f2bf(e);
            }
        }
    }
}

// ---------------------------------------------------------------------------
// K2 (fused): max-free flash attention + output projection + residual.
//   K/V staged per 64-key chunk via fully-coalesced global_load_lds (source
//   layouts chunk-interleaved to match lane order). 3 blocks/CU.
__global__ __launch_bounds__(256, 3) void k_attn_out(const u16* __restrict__ Qt,
        const u16* __restrict__ Kc, const u16* __restrict__ Vc,
        const u16* __restrict__ weff,
        const float* __restrict__ ob0, const float* __restrict__ ob1,
        const float* __restrict__ x0, const float* __restrict__ x1,
        float* __restrict__ out){
    __shared__ __align__(16) u16 kbuf[64*128];      // 16 KB: (cc,n) at (cc*64+n)*8
    __shared__ __align__(16) u16 vbuf[64*128];      // 16 KB: (pc,hc) at (pc*128+hc)*8
    __shared__ __align__(16) u16 smem[8*16*72];     // P tiles (dbuf/wave); H tile in epilogue
    int bx = blockIdx.x;                      // 576 = 8 XCD * 72
    int xcd = bx & 7, t = bx >> 3;
    int z  = xcd*2 + (t >= 36 ? 1 : 0);       // XCD x serves z in {2x,2x+1}
    int mt = (t >= 36) ? (t - 36) : t;
    int b = z >> 1, s = z & 1;
    const u16* Q = Qt + (size_t)(b*2 + (1 - s)) * (N_ * HID);
    const u16* K = Kc + (size_t)(b*2 + s)       * (N_ * HID);
    const u16* V = Vc + (size_t)(b*2 + s)       * (N_ * HID);
    const u16* Wf   = weff + (size_t)s * (C_ * HID);
    const float* bias = s ? ob1 : ob0;
    const float* X = (s ? x1 : x0) + (size_t)b * (C_ * N_);
    float* O = out + (size_t)s * ((size_t)B_ * C_ * N_) + (size_t)b * (C_ * N_);
    int lane = threadIdx.x & 63, wave = threadIdx.x >> 6;
    int l16 = lane & 15, quad = lane >> 4;
    int m0 = mt * 64 + wave * 16;

    bf8 aq[4];
    #pragma unroll
    for (int kk = 0; kk < 4; ++kk)
        aq[kk] = *reinterpret_cast<const bf8*>(&Q[(size_t)(m0 + l16)*HID + kk*32 + quad*8]);

    bf8 ones;
    #pragma unroll
    for (int j = 0; j < 8; ++j) ones[j] = (short)0x3F80;   // bf16 1.0

    f4 oacc[8];
    #pragma unroll
    for (int ct = 0; ct < 8; ++ct) oacc[ct] = f4{0,0,0,0};
    f4 sumacc = f4{0,0,0,0};

    const char* Kb = (const char*)K;
    const char* Vb = (const char*)V;

    for (int nc = 0; nc < N_/64; ++nc){
        __syncthreads();                      // previous chunk's LDS reads done
        // stage K tile: issue ik -> 1 KB contiguous burst
        #pragma unroll
        for (int j = 0; j < 4; ++j){
            int ik = wave*4 + j;
            dma16(Kb + ((size_t)(nc*16 + ik)*512 + lane*8)*2, &kbuf[ik*512]);
        }
        // stage V tile: issue iv -> 1 KB contiguous burst
        #pragma unroll
        for (int j = 0; j < 4; ++j){
            int iv = wave*4 + j;
            dma16(Vb + ((size_t)(nc*8 + (iv>>1))*1024 + (iv&1)*512 + lane*8)*2,
                  &vbuf[iv*512]);
        }
        __syncthreads();                      // drains vmcnt(0): tiles visible
        // QK
        f4 sacc[4] = {f4{0,0,0,0}, f4{0,0,0,0}, f4{0,0,0,0}, f4{0,0,0,0}};
        #pragma unroll
        for (int kk = 0; kk < 4; ++kk)
            #pragma unroll
            for (int nt = 0; nt < 4; ++nt){
                bf8 bk = *reinterpret_cast<const bf8*>(&kbuf[((kk*4+quad)*64 + nt*16 + l16)*8]);
                sacc[nt] = MFMA(aq[kk], bk, sacc[nt]);
            }
        // p = exp2(s), truncating bf16 store to per-wave LDS (double-buffered)
        u16* pw = smem + (wave*2 + (nc & 1)) * (16*72);
        #pragma unroll
        for (int nt = 0; nt < 4; ++nt)
            #pragma unroll
            for (int r = 0; r < 4; ++r)
                pw[(quad*4 + r)*72 + nt*16 + l16] = hi16(fexp2(sacc[nt][r]));
        // PV + rowsum
        #pragma unroll
        for (int kk2 = 0; kk2 < 2; ++kk2){
            bf8 ap = *reinterpret_cast<const bf8*>(&pw[l16*72 + kk2*32 + quad*8]);
            sumacc = MFMA(ap, ones, sumacc);
            #pragma unroll
            for (int ct = 0; ct < 8; ++ct){
                bf8 bv = *reinterpret_cast<const bf8*>(&vbuf[((kk2*4+quad)*128 + ct*16 + l16)*8]);
                oacc[ct] = MFMA(ap, bv, oacc[ct]);
            }
        }
    }

    // normalize (lane-local: sumacc has same C-layout as oacc) and stash H
    __syncthreads();                           // P region dead in all waves
    float inv[4];
    #pragma unroll
    for (int r = 0; r < 4; ++r) inv[r] = 1.0f / sumacc[r];
    #pragma unroll
    for (int ct = 0; ct < 8; ++ct)
        #pragma unroll
        for (int r = 0; r < 4; ++r)
            smem[(wave*16 + quad*4 + r)*136 + ct*16 + l16] = f2bf(oacc[ct][r] * inv[r]);
    __syncthreads();

    // out GEMM: wave w -> oc [w*64, w*64+64); K = HID = 128
    int mb = mt * 64;
    int oc0 = wave * 64;
    f4 acc2[4][4];
    #pragma unroll
    for (int ot = 0; ot < 4; ++ot)
        #pragma unroll
        for (int nt = 0; nt < 4; ++nt) acc2[ot][nt] = f4{0,0,0,0};
    #pragma unroll
    for (int kk = 0; kk < 4; ++kk){
        bf8 bh[4];
        #pragma unroll
        for (int nt = 0; nt < 4; ++nt)
            bh[nt] = *reinterpret_cast<const bf8*>(&smem[(nt*16 + l16)*136 + kk*32 + quad*8]);
        #pragma unroll
        for (int ot = 0; ot < 4; ++ot){
            bf8 a = *reinterpret_cast<const bf8*>(&Wf[(oc0 + ot*16 + l16)*HID + kk*32 + quad*8]);
            #pragma unroll
            for (int nt = 0; nt < 4; ++nt)
                acc2[ot][nt] = MFMA(a, bh[nt], acc2[ot][nt]);
        }
    }
    #pragma unroll
    for (int ot = 0; ot < 4; ++ot)
        #pragma unroll
        for (int nt = 0; nt < 4; ++nt){
            int m = mb + nt*16 + l16;
            #pragma unroll
            for (int r = 0; r < 4; ++r){
                int oc = oc0 + ot*16 + quad*4 + r;
                O[(size_t)oc*N_ + m] = acc2[ot][nt][r] + bias[oc] + X[(size_t)oc*N_ + m];
            }
        }
}

// ---------------------------------------------------------------------------
extern "C" void kernel_launch(void* const* d_in, const int* in_sizes, int n_in,
                              void* d_out, int out_size, void* d_ws, size_t ws_size,
                              hipStream_t stream){
    const float* x0  = (const float*)d_in[0];
    const float* x1  = (const float*)d_in[1];
    const float* ew0 = (const float*)d_in[2];
    const float* eb0 = (const float*)d_in[3];
    const float* ew1 = (const float*)d_in[4];
    const float* eb1 = (const float*)d_in[5];
    const float* ow0 = (const float*)d_in[6];
    const float* ob0 = (const float*)d_in[7];
    const float* ow1 = (const float*)d_in[8];
    const float* ob1 = (const float*)d_in[9];

    u16* ws = (u16*)d_ws;
    const size_t QT_E = (size_t)16 * N_ * HID;
    u16* Qt   = ws;
    u16* Kc   = Qt + QT_E;
    u16* Vc   = Kc + QT_E;
    u16* Wbf  = Vc + QT_E;
    u16* weff = Wbf + (size_t)2 * O3 * C_;
    u16* Xt   = (u16*)d_out;                  // scratch phase

    k_wcvt     <<<dim3(96, 2),     dim3(256), 0, stream>>>(ew0, ew1, Wbf);
    k_weff     <<<dim3(256),       dim3(256), 0, stream>>>(ow0, ow1, weff);
    k_transpose<<<dim3(36, 4, 16), dim3(256), 0, stream>>>(x0, x1, Xt);
    k_embed    <<<dim3(36, 6, 16), dim3(256), 0, stream>>>(Xt, Wbf, eb0, eb1, Qt, Kc, Vc);
    k_attn_out <<<dim3(576),       dim3(256), 0, stream>>>(Qt, Kc, Vc, weff, ob0, ob1,
                                                           x0, x1, (float*)d_out);
}